// Round 6
// baseline (167.929 us; speedup 1.0000x reference)
//
#include <hip/hip_runtime.h>
#include <hip/hip_bf16.h>
#include <stdint.h>

#define BATCH 256
#define PFD 128
#define T1 129
#define NPAIRS 1089      // 33*33
#define BH 72            // half-tile b_lds row stride (shorts): 64 k + 8 pad
#define CHUNK 8

typedef short bf16x8 __attribute__((ext_vector_type(8)));
typedef float f32x4 __attribute__((ext_vector_type(4)));

static __device__ __forceinline__ float float_of(unsigned u){ union{float f;unsigned u;}x;x.u=u;return x.f; }
static __device__ __forceinline__ unsigned pk_bf16(float a, float b){
  union { __hip_bfloat162 h; unsigned u; } c;
  c.h = __float22bfloat162_rn(make_float2(a, b));
  return c.u;
}

// global->LDS hardware DMA, 16B per lane. LDS dest = wave-uniform base
// (HW adds lane*16). Global src is per-lane. One instruction per wave -> +1 vmcnt.
static __device__ __forceinline__ void gl_lds16(const float* g, float* l) {
  __builtin_amdgcn_global_load_lds(
      (const __attribute__((address_space(1))) unsigned int*)g,
      (__attribute__((address_space(3))) unsigned int*)l,
      16, 0, 0);
}

// ---------------- Kernel 1: split-K fused trilinear GEMM ----------------
// m201-style counted-vmcnt pipeline at HALF-pair (32KB) granularity.
// Rounds 3/5 showed: supply width irrelevant (~1.9TB/s either way) because
// __syncthreads drains vmcnt every step, exposing each slab's supply with only
// the short compute phase as cover. Here the drain is counted:
//   B1: s_waitcnt vmcnt(4) lgkmcnt(0)  (slab s landed; slab s+1's 4 DMAs stay
//       in flight; vmcnt(0) only at the last step) + sched_barrier(0) +
//       raw s_barrier (NO automatic drain) + sched_barrier(0)
//   T:  fp32 [k][n] half-slab -> bf16 [n][k] b_lds[hb]  (ds ops only)
//   B2: lgkmcnt(0) + sched_barrier(0) + s_barrier + sched_barrier(0)
//   D:  issue DMA for half-slab s+2 into w_lds[hb] (safe: all waves' T reads
//       of w_lds[hb] retired before their B2; DMA data lands after issue)
//   C:  compute half-slab s (ds_read b_lds[hb] + 32 MFMA)
// b_lds[hb] reuse: C(s) reads retire before that wave's B2(s+1) lgkmcnt(0);
// next write is T(s+2) after B1(s+2) -> no overlap.
// vmcnt counting is safe w.r.t. older loads (rv/t/av issued before the primes
// are always drained first) and any spill traffic (only makes waits stronger).
// Round-4 lessons applied: no "memory" clobber on waitcnt asm, and
// sched_barrier(0) after every asm wait (guide rule #18).
__global__ __launch_bounds__(512, 2) void tfn_k1(
    const float* __restrict__ audio, const float* __restrict__ video,
    const float* __restrict__ text, const float* __restrict__ W1,
    unsigned short* __restrict__ part, int S) {
  __shared__ __align__(16) float w_lds[2][64 * 128];    // 2 x 32 KB fp32 half-slabs
  __shared__ __align__(16) short b_lds[2][PFD * BH];    // 2 x 18432 B bf16 [n][k]
  __shared__ __align__(16) float av_lds[BATCH * CHUNK]; // 8 KB

  const int tid = threadIdx.x;
  const int bk = blockIdx.x;
  const int npb = NPAIRS / S, rem0 = NPAIRS % S;
  const int p0 = bk * npb + (bk < rem0 ? bk : rem0);
  const int np = npb + (bk < rem0 ? 1 : 0);

  const int wave = tid >> 6, lane = tid & 63;
  const int l15 = lane & 15, quad = lane >> 4;
  const int sn = tid & 127, skg = tid >> 7;

  // t fragments in registers, fp32, MFMA A-layout: treg[mt][ks*8+j] = t(m, ks*32+quad*8+j)
  float treg[2][32];
  float t128r[2];
  #pragma unroll
  for (int mt = 0; mt < 2; ++mt) {
    const int m = wave * 32 + mt * 16 + l15;
    t128r[mt] = text[m * 128 + 127];
    #pragma unroll
    for (int ks = 0; ks < 4; ++ks)
      #pragma unroll
      for (int j = 0; j < 8; ++j) {
        const int it = ks * 32 + quad * 8 + j;
        treg[mt][ks * 8 + j] = (it == 0) ? 1.0f : text[m * 128 + it - 1];
      }
  }

  f32x4 acc[2][8];
  #pragma unroll
  for (int a = 0; a < 2; ++a)
    #pragma unroll
    for (int b = 0; b < 8; ++b) acc[a][b] = f32x4{0.f, 0.f, 0.f, 0.f};

  float rv[8];

  for (int c0 = 0; c0 < np; c0 += CHUNK) {
    const int nc = (np - c0) < CHUNK ? (np - c0) : CHUNK;
    const int pbase = p0 + c0;
    __syncthreads();   // chunk top (cold; nothing in flight -> free drain)
    if (tid < BATCH) {
      const int m = tid;
      for (int j = 0; j < nc; ++j) {
        int p = pbase + j;
        int ia = p / 33, iv = p - ia * 33;
        float a = (ia == 0) ? 1.0f : audio[m * 32 + ia - 1];
        float v = (iv == 0) ? 1.0f : video[m * 32 + iv - 1];
        av_lds[m * CHUNK + j] = a * v;
      }
    }
    // remainder row (it=128) — issued BEFORE the DMA primes, so these are
    // always older than any counted slab and get drained by the first wait.
    #pragma unroll
    for (int j = 0; j < 8; ++j) {
      int kk = skg * 8 + j;
      rv[j] = (kk < nc) ? W1[((long)(pbase + kk) * T1 + 128) * PFD + sn] : 0.0f;
    }

    // half-slab DMA: step s covers pair s>>1, k-rows (s&1)*64..+63 (32KB contig)
    auto dma_half = [&](int s, int hb) {
      const float* gsrc = W1 + (long)(pbase + (s >> 1)) * (T1 * PFD) + (s & 1) * (64 * PFD);
      #pragma unroll
      for (int g = 0; g < 4; ++g)
        gl_lds16(gsrc + g * 2048 + wave * 256 + lane * 4,
                 &w_lds[hb][g * 2048 + wave * 256]);
    };

    // prime: half-slabs 0 and 1 in flight (8 outstanding DMA ops/wave)
    dma_half(0, 0);
    dma_half(1, 1);

    const int NS = 2 * nc;
    for (int s = 0; s < NS; ++s) {
      const int hb = s & 1;
      // ---- B1: slab s landed (keep slab s+1 in flight); av/b ds-writes flushed
      if (s == NS - 1) { asm volatile("s_waitcnt vmcnt(0) lgkmcnt(0)"); }
      else             { asm volatile("s_waitcnt vmcnt(4) lgkmcnt(0)"); }
      __builtin_amdgcn_sched_barrier(0);
      __builtin_amdgcn_s_barrier();
      __builtin_amdgcn_sched_barrier(0);
      // ---- T: transpose half-slab hb: fp32 [k][n] -> bf16 [n][k]
      {
        union { bf16x8 v; unsigned u[4]; } w;
        #pragma unroll
        for (int g = 0; g < 2; ++g) {
          float f[8];
          #pragma unroll
          for (int j = 0; j < 8; ++j)
            f[j] = w_lds[hb][(g * 32 + skg * 8 + j) * 128 + sn];
          #pragma unroll
          for (int d = 0; d < 4; ++d) w.u[d] = pk_bf16(f[2 * d], f[2 * d + 1]);
          *(bf16x8*)&b_lds[hb][sn * BH + g * 32 + skg * 8] = w.v;
        }
      }
      // ---- B2: all waves done reading w_lds[hb] / writing b_lds[hb]
      asm volatile("s_waitcnt lgkmcnt(0)");
      __builtin_amdgcn_sched_barrier(0);
      __builtin_amdgcn_s_barrier();
      __builtin_amdgcn_sched_barrier(0);
      // ---- D: refill w_lds[hb] with half-slab s+2 (lands under C + next B1)
      if (s + 2 < NS) dma_half(s + 2, hb);
      // ---- C: compute half-slab s (pair sp, k-half h)
      {
        const int sp = s >> 1, h = s & 1;
        const float avm0 = av_lds[(wave * 32 + l15) * CHUNK + sp];
        const float avm1 = av_lds[(wave * 32 + 16 + l15) * CHUNK + sp];
        #pragma unroll
        for (int ksl = 0; ksl < 2; ++ksl) {
          const int ks = h * 2 + ksl;
          bf16x8 A0, A1;
          {
            union { bf16x8 v; unsigned u[4]; } c0u, c1u;
            #pragma unroll
            for (int d = 0; d < 4; ++d) {
              c0u.u[d] = pk_bf16(avm0 * treg[0][ks * 8 + 2 * d], avm0 * treg[0][ks * 8 + 2 * d + 1]);
              c1u.u[d] = pk_bf16(avm1 * treg[1][ks * 8 + 2 * d], avm1 * treg[1][ks * 8 + 2 * d + 1]);
            }
            A0 = c0u.v; A1 = c1u.v;
          }
          #pragma unroll
          for (int nt = 0; nt < 8; ++nt) {
            bf16x8 bf = *(const bf16x8*)&b_lds[hb][(nt * 16 + l15) * BH + ksl * 32 + quad * 8];
            acc[0][nt] = __builtin_amdgcn_mfma_f32_16x16x32_bf16(A0, bf, acc[0][nt], 0, 0, 0);
            acc[1][nt] = __builtin_amdgcn_mfma_f32_16x16x32_bf16(A1, bf, acc[1][nt], 0, 0, 0);
          }
        }
      }
    }

    // ---- remainder tile: it=128, k-slot = pair index within chunk ----
    __syncthreads();   // cold path; nothing in flight (vmcnt(0) at last step)
    {
      union { bf16x8 v; unsigned u[4]; } w;
      #pragma unroll
      for (int d = 0; d < 4; ++d) w.u[d] = pk_bf16(rv[2 * d], rv[2 * d + 1]);
      *(bf16x8*)&b_lds[0][sn * BH + skg * 8] = w.v;
    }
    __syncthreads();
    {
      bf16x8 A[2];
      #pragma unroll
      for (int mt = 0; mt < 2; ++mt) {
        const int m = wave * 32 + mt * 16 + l15;
        union { bf16x8 v; unsigned u[4]; } c;
        #pragma unroll
        for (int d = 0; d < 4; ++d) {
          int k0 = quad * 8 + 2 * d, k1 = k0 + 1;
          float f0 = (k0 < nc) ? av_lds[m * CHUNK + k0] * t128r[mt] : 0.0f;
          float f1 = (k1 < nc) ? av_lds[m * CHUNK + k1] * t128r[mt] : 0.0f;
          c.u[d] = pk_bf16(f0, f1);
        }
        A[mt] = c.v;
      }
      #pragma unroll
      for (int nt = 0; nt < 8; ++nt) {
        bf16x8 bf = *(const bf16x8*)&b_lds[0][(nt * 16 + l15) * BH + quad * 8];
        acc[0][nt] = __builtin_amdgcn_mfma_f32_16x16x32_bf16(A[0], bf, acc[0][nt], 0, 0, 0);
        acc[1][nt] = __builtin_amdgcn_mfma_f32_16x16x32_bf16(A[1], bf, acc[1][nt], 0, 0, 0);
      }
    }
  }

  // writeback: bf16, m-major [m][S][phys_n], phys n = l15*8 + nt
  #pragma unroll
  for (int mt = 0; mt < 2; ++mt)
    #pragma unroll
    for (int r = 0; r < 4; ++r) {
      const int m = wave * 32 + mt * 16 + quad * 4 + r;
      union { bf16x8 v; unsigned u[4]; } w;
      #pragma unroll
      for (int d = 0; d < 4; ++d) w.u[d] = pk_bf16(acc[mt][2 * d][r], acc[mt][2 * d + 1][r]);
      *(bf16x8*)&part[((size_t)m * S + bk) * PFD + l15 * 8] = w.v;
    }
}

// ---------------- Kernel 2: contiguous reduce + bias/relu + layers 2,3 ----------------
__global__ __launch_bounds__(1024) void tfn_k2(
    const unsigned short* __restrict__ part, const float* __restrict__ b1,
    const float* __restrict__ W2, const float* __restrict__ b2,
    const float* __restrict__ W3, const float* __restrict__ b3,
    float* __restrict__ out, int S) {
  __shared__ float sred[1024 * 4];   // 16 KB
  __shared__ float h1s[PFD];
  __shared__ float a2s[1024];
  __shared__ float red[2];
  const int m = blockIdx.x, tid = threadIdx.x;
  const int g = tid & 31, q = tid >> 5;       // 32 s-groups of 32 slabs
  const unsigned short* base = part + (size_t)m * S * PFD;
  float s0 = 0, s1 = 0, s2 = 0, s3 = 0;
  for (int bkk = q; bkk < S; bkk += 32) {
    uint2 v = *(const uint2*)&base[(size_t)bkk * PFD + g * 4];
    s0 += float_of(v.x << 16);
    s1 += float_of(v.x & 0xFFFF0000u);
    s2 += float_of(v.y << 16);
    s3 += float_of(v.y & 0xFFFF0000u);
  }
  sred[tid * 4 + 0] = s0; sred[tid * 4 + 1] = s1;
  sred[tid * 4 + 2] = s2; sred[tid * 4 + 3] = s3;
  __syncthreads();
  if (tid < PFD) {
    const int p = tid;
    float h = 0;
    #pragma unroll
    for (int bl = 0; bl < 32; ++bl) h += sred[(bl * 32 + (p >> 2)) * 4 + (p & 3)];
    const int n = (p & 7) * 16 + (p >> 3);   // un-swizzle phys -> logical
    h1s[n] = fmaxf(h + b1[n], 0.0f);
  }
  __syncthreads();
  const int n = tid & 127, kq = tid >> 7;    // 8 k-groups of 16
  float a2 = 0.0f;
  const int k0 = kq * 16;
  #pragma unroll
  for (int k = 0; k < 16; ++k) a2 += h1s[k0 + k] * W2[(k0 + k) * PFD + n];
  a2s[tid] = a2;
  __syncthreads();
  if (tid < 128) {
    float h2 = 0.0f;
    #pragma unroll
    for (int j = 0; j < 8; ++j) h2 += a2s[n + 128 * j];
    h2 = fmaxf(h2 + b2[n], 0.0f);
    float pr = h2 * W3[n];
    #pragma unroll
    for (int off = 32; off > 0; off >>= 1) pr += __shfl_down(pr, off);
    if ((tid & 63) == 0) red[tid >> 6] = pr;
  }
  __syncthreads();
  if (tid == 0) out[m] = red[0] + red[1] + b3[0];
}

extern "C" void kernel_launch(void* const* d_in, const int* in_sizes, int n_in,
                              void* d_out, int out_size, void* d_ws, size_t ws_size,
                              hipStream_t stream) {
  const float* audio = (const float*)d_in[0];
  const float* video = (const float*)d_in[1];
  const float* text  = (const float*)d_in[2];
  const float* W1 = (const float*)d_in[3];
  const float* b1 = (const float*)d_in[4];
  const float* W2 = (const float*)d_in[5];
  const float* b2 = (const float*)d_in[6];
  const float* W3 = (const float*)d_in[7];
  const float* b3 = (const float*)d_in[8];
  unsigned short* part = (unsigned short*)d_ws;

  const size_t slab = (size_t)BATCH * PFD * sizeof(unsigned short);  // 64 KB
  int S = (int)(ws_size / slab);
  if (S > 256) S = 256;   // 1 block/CU forced by regs; one round, min fixed overhead
  if (S < 1) S = 1;

  tfn_k1<<<S, 512, 0, stream>>>(audio, video, text, W1, part, S);
  tfn_k2<<<BATCH, 1024, 0, stream>>>(part, b1, W2, b2, W3, b3, (float*)d_out, S);
}